// Round 5
// baseline (157.131 us; speedup 1.0000x reference)
//
#include <hip/hip_runtime.h>

#define T_ 2048
#define B_ 2
#define H_ 12
#define C_ 768
#define M_ 4096  // B*T
#define BH_ (B_ * H_)
#define RSTR 2200  // reversed-e padded stride

typedef __attribute__((ext_vector_type(4))) float f32x4;
typedef __attribute__((ext_vector_type(16))) float f32x16;
typedef __attribute__((ext_vector_type(8))) __bf16 bf16x8;
typedef __attribute__((ext_vector_type(4))) __bf16 bf16x4;

// Packed fragment-major layouts (coalesced MFMA frag loads: addr = base + lane*8 elems):
//  Qp/Kp: [bh][tile=t>>5][kc=d>>4][lane=((d>>3)&1)*32 + (t&31)][j=d&7]   (tile stride 2048)
//  Vp:    [bh][chunk=t>>6][dhalf=d>>5][kc=(t&63)>>4][lane=(((t&63)>>3)&1)*32 + (d&31)][j=t&7]

// ---------------------------------------------------------------------------
// Stage-1 GEMM: qkv = x @ c_attn^T -> packed bf16 Qp, Kp, Vp
// ---------------------------------------------------------------------------
__global__ __launch_bounds__(256) void gemm_qkv(const float* __restrict__ A,
                                                const float* __restrict__ Bm,
                                                __bf16* __restrict__ Qp,
                                                __bf16* __restrict__ Kp,
                                                __bf16* __restrict__ Vp) {
  __shared__ __align__(16) __bf16 sA[128][40];
  __shared__ __align__(16) __bf16 sB[128][40];
  const int tid = threadIdx.x;
  const int m0 = blockIdx.y * 128, n0 = blockIdx.x * 128;
  const int lane = tid & 63, w = tid >> 6;
  const int wr = w >> 1, wc = w & 1;
  const int fr = lane & 15;
  const int ko = (lane >> 4) << 3;
  const int K = C_;
  f32x4 acc[4][4] = {};
  for (int k0 = 0; k0 < K; k0 += 32) {
#pragma unroll
    for (int i = 0; i < 4; ++i) {
      int f = tid + (i << 8);
      int row = f >> 3, c4 = (f & 7) << 2;
      f32x4 av = *(const f32x4*)(A + (size_t)(m0 + row) * K + k0 + c4);
      f32x4 bv = *(const f32x4*)(Bm + (size_t)(n0 + row) * K + k0 + c4);
      bf16x4 ah, bh;
#pragma unroll
      for (int j = 0; j < 4; ++j) { ah[j] = (__bf16)av[j]; bh[j] = (__bf16)bv[j]; }
      *(bf16x4*)&sA[row][c4] = ah;
      *(bf16x4*)&sB[row][c4] = bh;
    }
    __syncthreads();
    bf16x8 a[4], b[4];
#pragma unroll
    for (int m = 0; m < 4; ++m) a[m] = *(const bf16x8*)&sA[wr * 64 + m * 16 + fr][ko];
#pragma unroll
    for (int n = 0; n < 4; ++n) b[n] = *(const bf16x8*)&sB[wc * 64 + n * 16 + fr][ko];
#pragma unroll
    for (int m = 0; m < 4; ++m)
#pragma unroll
      for (int n = 0; n < 4; ++n)
        acc[m][n] = __builtin_amdgcn_mfma_f32_16x16x32_bf16(a[m], b[n], acc[m][n], 0, 0, 0);
    __syncthreads();
  }
  const int orow = (lane >> 4) << 2, ocol = lane & 15;
#pragma unroll
  for (int m = 0; m < 4; ++m)
#pragma unroll
    for (int n = 0; n < 4; ++n) {
      int r = m0 + wr * 64 + m * 16 + orow;  // token (4 consecutive via j)
      int c = n0 + wc * 64 + n * 16 + ocol;  // feature
      int sec = c / 768;
      int hd = c - sec * 768;
      int h = hd >> 6, d = hd & 63;
      int b = r >> 11, t = r & 2047;
      int bh = b * H_ + h;
      if (sec < 2) {
        int tile = t >> 5, rr = t & 31;
        int kc = d >> 4, half = (d >> 3) & 1, dj = d & 7;
        __bf16* dst = (sec == 0 ? Qp : Kp) + ((size_t)bh * 64 + tile) * 2048 +
                      kc * 512 + (half * 32 + rr) * 8 + dj;
#pragma unroll
        for (int j = 0; j < 4; ++j) dst[j * 8] = (__bf16)acc[m][n][j];  // rr+j
      } else {
        int chunk = t >> 6, sk = t & 63;
        int kc = sk >> 4, hf = (sk >> 3) & 1, j0 = sk & 7;  // j0 in {0,4}
        bf16x4 pk;
#pragma unroll
        for (int j = 0; j < 4; ++j) pk[j] = (__bf16)acc[m][n][j];
        *(bf16x4*)(Vp + ((size_t)bh * 32 + chunk) * 4096 + (d >> 5) * 2048 +
                   kc * 512 + (hf * 32 + (d & 31)) * 8 + j0) = pk;
      }
    }
}

// ---------------------------------------------------------------------------
// Stage-2 GEMM: C[M,N] = A[M,K] * B[N,K]^T
// ---------------------------------------------------------------------------
__global__ __launch_bounds__(256) void gemm_bt(const float* __restrict__ A,
                                               const float* __restrict__ Bm,
                                               float* __restrict__ C,
                                               int M, int N, int K) {
  __shared__ __align__(16) __bf16 sA[128][40];
  __shared__ __align__(16) __bf16 sB[128][40];
  const int tid = threadIdx.x;
  const int m0 = blockIdx.y * 128, n0 = blockIdx.x * 128;
  const int lane = tid & 63, w = tid >> 6;
  const int wr = w >> 1, wc = w & 1;
  const int fr = lane & 15;
  const int ko = (lane >> 4) << 3;
  f32x4 acc[4][4] = {};
  for (int k0 = 0; k0 < K; k0 += 32) {
#pragma unroll
    for (int i = 0; i < 4; ++i) {
      int f = tid + (i << 8);
      int row = f >> 3, c4 = (f & 7) << 2;
      f32x4 av = *(const f32x4*)(A + (size_t)(m0 + row) * K + k0 + c4);
      f32x4 bv = *(const f32x4*)(Bm + (size_t)(n0 + row) * K + k0 + c4);
      bf16x4 ah, bh;
#pragma unroll
      for (int j = 0; j < 4; ++j) { ah[j] = (__bf16)av[j]; bh[j] = (__bf16)bv[j]; }
      *(bf16x4*)&sA[row][c4] = ah;
      *(bf16x4*)&sB[row][c4] = bh;
    }
    __syncthreads();
    bf16x8 a[4], b[4];
#pragma unroll
    for (int m = 0; m < 4; ++m) a[m] = *(const bf16x8*)&sA[wr * 64 + m * 16 + fr][ko];
#pragma unroll
    for (int n = 0; n < 4; ++n) b[n] = *(const bf16x8*)&sB[wc * 64 + n * 16 + fr][ko];
#pragma unroll
    for (int m = 0; m < 4; ++m)
#pragma unroll
      for (int n = 0; n < 4; ++n)
        acc[m][n] = __builtin_amdgcn_mfma_f32_16x16x32_bf16(a[m], b[n], acc[m][n], 0, 0, 0);
    __syncthreads();
  }
  const int orow = (lane >> 4) << 2, ocol = lane & 15;
#pragma unroll
  for (int m = 0; m < 4; ++m)
#pragma unroll
    for (int n = 0; n < 4; ++n) {
      int r = m0 + wr * 64 + m * 16 + orow;
      int c = n0 + wc * 64 + n * 16 + ocol;
#pragma unroll
      for (int j = 0; j < 4; ++j) C[(size_t)(r + j) * N + c] = acc[m][n][j];
    }
}

// ---------------------------------------------------------------------------
// corr: diagonal-band MFMA, branch-free straight-line deep pipeline.
// All loads unconditional (si clamped to 0, zero-selected after) so the
// compiler emits one straight-line block with counted vmcnt; 36+32 loads
// in flight instead of ~8. grid = 864 = 8 XCD x (3 bh x 36 (qb,tc)).
// ---------------------------------------------------------------------------
__global__ __launch_bounds__(256) void corr_k(const __bf16* __restrict__ Qp,
                                              const __bf16* __restrict__ Kp,
                                              float* __restrict__ P) {
  __shared__ float swc[4][128];
  const int tid = threadIdx.x;
  int id = blockIdx.x;
  int sub = id >> 3;
  const int bh = (id & 7) * 3 + sub / 36;
  const int pi = sub % 36;
  int x = pi, qb = 0;
  while (x >= 8 - qb) { x -= 8 - qb; ++qb; }
  const int tc = qb + x;
  const int lane = tid & 63, w = tid >> 6;

  for (int i = tid; i < 512; i += 256) ((float*)swc)[i] = 0.f;

  const __bf16* qp = Qp + ((size_t)bh << 17) + (lane << 3);
  const __bf16* kp = Kp + ((size_t)bh << 17) + (lane << 3);
  const int qA = 8 * qb + 2 * w;
  const int t0 = 8 * tc;
  const int si0 = t0 - qA;
  f32x16 acc0 = {}, acc1 = {};
  const bf16x8 zf = {};

#define QSET(NM, TI)                                                        \
  bf16x8 NM##0, NM##1, NM##2, NM##3;                                        \
  {                                                                         \
    const __bf16* r_ = qp + (size_t)(TI) * 2048;                            \
    NM##0 = *(const bf16x8*)(r_);        NM##1 = *(const bf16x8*)(r_ + 512);\
    NM##2 = *(const bf16x8*)(r_ + 1024); NM##3 = *(const bf16x8*)(r_ + 1536);\
  }
#define KSET(NM, SI)                                                        \
  bf16x8 NM##0, NM##1, NM##2, NM##3;                                        \
  {                                                                         \
    const int si_ = (SI);                                                   \
    const __bf16* r_ = kp + (size_t)(si_ > 0 ? si_ : 0) * 2048;             \
    NM##0 = *(const bf16x8*)(r_);        NM##1 = *(const bf16x8*)(r_ + 512);\
    NM##2 = *(const bf16x8*)(r_ + 1024); NM##3 = *(const bf16x8*)(r_ + 1536);\
    if (si_ < 0) { NM##0 = zf; NM##1 = zf; NM##2 = zf; NM##3 = zf; }        \
  }
#define TISTEP(QN, KC, KP)                                                          \
  acc0 = __builtin_amdgcn_mfma_f32_32x32x16_bf16(QN##0, KC##0, acc0, 0, 0, 0);      \
  acc1 = __builtin_amdgcn_mfma_f32_32x32x16_bf16(QN##0, KP##0, acc1, 0, 0, 0);      \
  acc0 = __builtin_amdgcn_mfma_f32_32x32x16_bf16(QN##1, KC##1, acc0, 0, 0, 0);      \
  acc1 = __builtin_amdgcn_mfma_f32_32x32x16_bf16(QN##1, KP##1, acc1, 0, 0, 0);      \
  acc0 = __builtin_amdgcn_mfma_f32_32x32x16_bf16(QN##2, KC##2, acc0, 0, 0, 0);      \
  acc1 = __builtin_amdgcn_mfma_f32_32x32x16_bf16(QN##2, KP##2, acc1, 0, 0, 0);      \
  acc0 = __builtin_amdgcn_mfma_f32_32x32x16_bf16(QN##3, KC##3, acc0, 0, 0, 0);      \
  acc1 = __builtin_amdgcn_mfma_f32_32x32x16_bf16(QN##3, KP##3, acc1, 0, 0, 0);

  // phase 1: 9 frag-sets in flight (36 loads)
  QSET(qq0, t0)     QSET(qq1, t0 + 1) QSET(qq2, t0 + 2) QSET(qq3, t0 + 3)
  KSET(kkm, si0 - 1) KSET(kk0, si0)   KSET(kk1, si0 + 1) KSET(kk2, si0 + 2)
  KSET(kk3, si0 + 3)
  // compute ti0, ti1 (frees qq0, qq1, kkm, kk0)
  TISTEP(qq0, kk0, kkm)
  TISTEP(qq1, kk1, kk0)
  // phase 2: 8 more frag-sets issued mid-stream (32 loads)
  QSET(qq4, t0 + 4) QSET(qq5, t0 + 5) QSET(qq6, t0 + 6) QSET(qq7, t0 + 7)
  KSET(kk4, si0 + 4) KSET(kk5, si0 + 5) KSET(kk6, si0 + 6) KSET(kk7, si0 + 7)
  // remaining compute
  TISTEP(qq2, kk2, kk1)
  TISTEP(qq3, kk3, kk2)
  TISTEP(qq4, kk4, kk3)
  TISTEP(qq5, kk5, kk4)
  TISTEP(qq6, kk6, kk5)
  TISTEP(qq7, kk7, kk6)
#undef QSET
#undef KSET
#undef TISTEP

  __syncthreads();
  const int col = lane & 31, rb = (lane >> 5) << 2;
#pragma unroll
  for (int j = 0; j < 16; ++j) {
    int row = (j & 3) + ((j >> 2) << 3) + rb;
    atomicAdd(&swc[w][row - col + 31], acc0[j]);   // band qA
    atomicAdd(&swc[w][row - col + 63], acc1[j]);   // band qA+1
  }
  __syncthreads();

  // merge wave regions; write FULL row of unique slice pi (zeros elsewhere)
  float* Pd = P + ((size_t)pi * BH_ + bh) * T_;
  float ov[8];
#pragma unroll
  for (int u = 0; u < 8; ++u) {
    int L = (tid << 3) + u;
    int l = L - 256 * qb;
    float s = 0.f;
    if (l >= -31 && l < 256) {
#pragma unroll
      for (int ww = 0; ww < 4; ++ww) {
        int r = l - 64 * ww + 31;
        if (r >= 0 && r < 95) s += swc[ww][r];
      }
    }
    ov[u] = s;
  }
  *(f32x4*)(Pd + (tid << 3)) = *(f32x4*)&ov[0];
  *(f32x4*)(Pd + (tid << 3) + 4) = *(f32x4*)&ov[4];
}

// ---------------------------------------------------------------------------
// soft_k: reduce 36 partial slices -> Rb (8 phase-shifted reversed-e, bf16)
// and zinv = 1/Z.
// ---------------------------------------------------------------------------
__global__ __launch_bounds__(256) void soft_k(const float* __restrict__ P,
                                              const float* __restrict__ temp,
                                              __bf16* __restrict__ Rb,
                                              float* __restrict__ zinv) {
  __shared__ float se[T_];
  __shared__ float lm[4], wsum[4];
  const int bh = blockIdx.x, tid = threadIdx.x;
  const int lane = tid & 63, wid = tid >> 6;
  const float scale = 1.0f / (64.0f * (temp[0] + 1e-6f));
  f32x4 sa = {}, sb = {};
#pragma unroll
  for (int j = 0; j < 36; ++j) {
    const float* pp = P + ((size_t)j * BH_ + bh) * T_ + (tid << 3);
    sa += *(const f32x4*)pp;
    sb += *(const f32x4*)(pp + 4);
  }
  float v[8];
#pragma unroll
  for (int i = 0; i < 4; ++i) { v[i] = sa[i] * scale; v[4 + i] = sb[i] * scale; }
  float m = v[0];
#pragma unroll
  for (int i = 1; i < 8; ++i) m = fmaxf(m, v[i]);
#pragma unroll
  for (int off = 1; off < 64; off <<= 1) m = fmaxf(m, __shfl_xor(m, off));
  if (lane == 0) lm[wid] = m;
  __syncthreads();
  m = fmaxf(fmaxf(lm[0], lm[1]), fmaxf(lm[2], lm[3]));
  float ex[8], pr[8], run = 0;
#pragma unroll
  for (int i = 0; i < 8; ++i) { ex[i] = __expf(v[i] - m); run += ex[i]; pr[i] = run; }
  float s = run;
  for (int off = 1; off < 64; off <<= 1) {
    float o = __shfl_up(s, off);
    if (lane >= off) s += o;
  }
  if (lane == 63) wsum[wid] = s;
  __syncthreads();
  float base = s - run;
  for (int jw = 0; jw < wid; ++jw) base += wsum[jw];
#pragma unroll
  for (int i = 0; i < 8; ++i) {
    int t = (tid << 3) + i;
    zinv[(size_t)bh * T_ + t] = 1.0f / (base + pr[i]);
    se[t] = ex[i];
  }
  __syncthreads();
  __bf16* rb = Rb + (size_t)bh * 8 * RSTR;
  for (int c = tid; c < RSTR / 8; c += 256) {
    int i0 = c << 3;
#pragma unroll
    for (int p = 0; p < 8; ++p) {
      bf16x8 ovv;
#pragma unroll
      for (int e = 0; e < 8; ++e) {
        int idx = T_ - 1 - p - (i0 + e);
        ovv[e] = (__bf16)((idx >= 0) ? se[idx] : 0.f);
      }
      *(bf16x8*)(rb + p * RSTR + i0) = ovv;
    }
  }
}

// ---------------------------------------------------------------------------
// conv: Toeplitz MFMA, triple-buffered V-chunk pipeline (prefetch distance 3).
// A-frags from LDS reversed-e; B-frags coalesced from packed Vp.
// grid = 384 = 8 x (3 bh x 16 pairs), paired t-blocks {i,31-i} load-balance.
// ---------------------------------------------------------------------------
__global__ __launch_bounds__(256) void conv_k(const __bf16* __restrict__ Vp,
                                              const __bf16* __restrict__ Rb,
                                              const float* __restrict__ zinv,
                                              float* __restrict__ y2) {
  __shared__ __align__(16) __bf16 revc[8 * RSTR];
  const int tid = threadIdx.x;
  int id = blockIdx.x;
  int sub = id >> 3;
  const int bh = (id & 7) * 3 + (sub >> 4);
  const int pr = sub & 15;
  const int lane = tid & 63, w = tid >> 6;

  const __bf16* rb = Rb + (size_t)bh * 8 * RSTR;
  for (int c = tid; c < RSTR; c += 256)
    *(bf16x8*)&revc[c << 3] = *(const bf16x8*)(rb + ((size_t)c << 3));
  __syncthreads();

  const int fr = lane & 31, kg = (lane >> 5) << 3;
  const int tt = (w < 2) ? (64 * pr + 32 * w) : (64 * (31 - pr) + 32 * (w - 2));
  const int trow = tt + fr;
  const int pp = (T_ - 1 - trow) & 7;
  const int obase = (T_ - 1 - trow) - pp;
  const __bf16* vpb = Vp + (size_t)bh * 131072 + (lane << 3);
  f32x16 acc0 = {}, acc1 = {};
  const int nst = (tt >> 6) + 1;

  bf16x8 A00, A01, A02, A03, A10, A11, A12, A13;
  bf16x8 B00, B01, B02, B03, B10, B11, B12, B13;
  bf16x8 C00, C01, C02, C03, C10, C11, C12, C13;

#define LOADV(P, CH)                                                          \
  {                                                                           \
    const __bf16* vb_ = vpb + (size_t)(CH) * 4096;                            \
    P##00 = *(const bf16x8*)(vb_);          P##01 = *(const bf16x8*)(vb_ + 512);  \
    P##02 = *(const bf16x8*)(vb_ + 1024);   P##03 = *(const bf16x8*)(vb_ + 1536); \
    P##10 = *(const bf16x8*)(vb_ + 2048);   P##11 = *(const bf16x8*)(vb_ + 2560); \
    P##12 = *(const bf16x8*)(vb_ + 3072);   P##13 = *(const bf16x8*)(vb_ + 3584); \
  }
#define MSTEP(P, ST)                                                          \
  {                                                                           \
    const int ab_ = pp * RSTR + obase + (ST) * 64 + kg;                       \
    bf16x8 a0_ = *(const bf16x8*)&revc[ab_];                                  \
    bf16x8 a1_ = *(const bf16x8*)&revc[ab_ + 16];                             \
    bf16x8 a2_ = *(const bf16x8*)&revc[ab_ + 32];                             \
    bf16x8 a3_ = *(const bf16x8*)&revc[ab_ + 48];                             \
    acc0 = __builtin_amdgcn_mfma_f32_32x32x16_bf16(a0_, P##00, acc0, 0, 0, 0);\
    acc1 = __builtin_amdgcn_mfma_f32_32x32x16_bf16(a0_, P##10, acc1, 0, 0, 0);\
    acc0 = __builtin_amdgcn_mfma_f32_32x32x16_bf16(a1_, P##01, acc0, 0, 0, 0);\
    acc1 = __builtin_amdgcn_mfma_f32_32x32x16_bf16(a1_, P##11, acc1, 0, 0, 0);\
    acc0 = __builtin_amdgcn_mfma_f32_32x32x16_bf16(a2_, P##02, acc0, 0, 0, 0);\
    acc1 = __builtin_amdgcn_mfma_f32_32x32x16_bf16(a2_, P##12, acc1, 0, 0, 0);\
    acc0 = __builtin_amdgcn_mfma_f32_32x32x16_bf16(a3_, P##03, acc0, 0, 0, 0);\
    acc1 = __builtin_amdgcn_mfma_f32_32x32x16_bf16(a3_, P##13, acc1, 0, 0, 0);\
  }

  LOADV(A, 0);
  if (nst > 1) LOADV(B, 1);
  if (nst > 2) LOADV(C, 2);
  int st = 0;
  while (true) {
    MSTEP(A, st); if (st + 3 < nst) LOADV(A, st + 3); if (++st >= nst) break;
    MSTEP(B, st); if (st + 3 < nst) LOADV(B, st + 3); if (++st >= nst) break;
    MSTEP(C, st); if (st + 3 < nst) LOADV(C, st + 3); if (++st >= nst) break;
  }
#undef LOADV
#undef MSTEP

  const int b = bh / H_, h = bh % H_;
  const int ocol = lane & 31, rbj = (lane >> 5) << 2;
  const float* zp = zinv + (size_t)bh * T_;
#pragma unroll
  for (int j = 0; j < 16; ++j) {
    int row = (j & 3) + ((j >> 2) << 3) + rbj;
    int t = tt + row;
    float zi = zp[t];
    float* yr = y2 + ((size_t)b * T_ + t) * C_ + h * 64;
    yr[ocol] = acc0[j] * zi;
    yr[32 + ocol] = acc1[j] * zi;
  }
}

// ---------------------------------------------------------------------------
extern "C" void kernel_launch(void* const* d_in, const int* in_sizes, int n_in,
                              void* d_out, int out_size, void* d_ws, size_t ws_size,
                              hipStream_t stream) {
  const float* x = (const float*)d_in[0];
  const float* c_attn = (const float*)d_in[1];
  const float* c_proj = (const float*)d_in[2];
  const float* temp = (const float*)d_in[3];
  float* out = (float*)d_out;

  // ws: Qp|Kp|Vp (3 x 3.145M bf16) | Rb | zinv | y2 | P36  (~39.7 MB)
  __bf16* Qp = (__bf16*)d_ws;
  __bf16* Kp = Qp + (size_t)BH_ * 64 * 2048;
  __bf16* Vp = Kp + (size_t)BH_ * 64 * 2048;
  __bf16* Rb = Vp + (size_t)BH_ * 32 * 4096;
  float* zinv = (float*)(Rb + (size_t)BH_ * 8 * RSTR);
  float* y2 = zinv + (size_t)BH_ * T_;
  float* P = y2 + (size_t)M_ * C_;

  gemm_qkv<<<dim3(2304 / 128, M_ / 128), 256, 0, stream>>>(x, c_attn, Qp, Kp, Vp);
  corr_k<<<dim3(864), 256, 0, stream>>>(Qp, Kp, P);
  soft_k<<<dim3(BH_), 256, 0, stream>>>(P, temp, Rb, zinv);
  conv_k<<<dim3(384), 256, 0, stream>>>(Vp, Rb, zinv, y2);
  gemm_bt<<<dim3(C_ / 128, M_ / 128), 256, 0, stream>>>(y2, c_proj, out, M_, C_, C_);
}